// Round 10
// baseline (801.544 us; speedup 1.0000x reference)
//
#include <hip/hip_runtime.h>

typedef _Float16 half_t;
typedef _Float16 half8 __attribute__((ext_vector_type(8)));
typedef float floatx4 __attribute__((ext_vector_type(4)));

#define MFMA(a,b,c) __builtin_amdgcn_mfma_f32_16x16x32_f16(a,b,c,0,0,0)

#define NB 16
#define NLEN 1024
#define DD 128
#define BN (NB*NLEN)                       // 16384 rows per branch
#define BND ((size_t)NB*NLEN*DD)
#define EMP 1044                           // emS row stride

// ---------------- weight casts: gW->Wf16, gA+gA^T->ST16, Ew->EwF
__global__ __launch_bounds__(256)
void k_cast(const float* __restrict__ gW, const float* __restrict__ gA,
            const float* __restrict__ Ew,
            half_t* __restrict__ Wf, half_t* __restrict__ STf, half_t* __restrict__ EwF) {
    int i = blockIdx.x * 256 + threadIdx.x;
    if (i < 65536) {
        Wf[i] = (half_t)gW[i];
        int base = i & ~16383;
        int lrem = i & 16383;
        int d = lrem >> 7, e = lrem & 127;
        STf[base + (e << 7) + d] = (half_t)(gA[i] + gA[base + (e << 7) + d]);
    } else {
        int j = i - 65536;
        EwF[j] = (half_t)Ew[j];
    }
}

// ---------------- embed as MFMA GEMM: h16 = f16(x) @ EwF^T
__global__ __launch_bounds__(256)
void k_emb(const float* __restrict__ x, const half_t* __restrict__ EwF,
           half_t* __restrict__ h16) {
    __shared__ half_t htile[32 * 136];
    __shared__ half_t otile[32 * 136];
    int g = blockIdx.x * 32;
    int t = threadIdx.x;
    int w = t >> 6, l = t & 63, q = l >> 4, l15 = l & 15;
#pragma unroll
    for (int v = 0; v < 2; v++) {
        int idx = v * 256 + t; int r = idx >> 4, c8 = (idx & 15) * 8;
        const float* xp = &x[(size_t)(g + r) * DD + c8];
        float4 f0 = *(const float4*)xp;
        float4 f1 = *(const float4*)(xp + 4);
        half8 va;
        va[0] = (half_t)f0.x; va[1] = (half_t)f0.y; va[2] = (half_t)f0.z; va[3] = (half_t)f0.w;
        va[4] = (half_t)f1.x; va[5] = (half_t)f1.y; va[6] = (half_t)f1.z; va[7] = (half_t)f1.w;
        *(half8*)&htile[r * 136 + c8] = va;
    }
    __syncthreads();
    int rowh = (w & 1) * 16;
    int c0 = (w >> 1) * 4;
    half8 a1[4];
#pragma unroll
    for (int kc = 0; kc < 4; kc++) a1[kc] = *(const half8*)&htile[(rowh + l15) * 136 + kc * 32 + q * 8];
#pragma unroll
    for (int cc = 0; cc < 4; cc++) {
        int col = (c0 + cc) * 16 + l15;
        floatx4 a = {0.f, 0.f, 0.f, 0.f};
#pragma unroll
        for (int kc = 0; kc < 4; kc++) {
            half8 bf = *(const half8*)&EwF[((size_t)col << 7) + kc * 32 + q * 8];
            a = MFMA(a1[kc], bf, a);
        }
#pragma unroll
        for (int r = 0; r < 4; r++)
            otile[(rowh + q * 4 + r) * 136 + col] = (half_t)a[r];
    }
    __syncthreads();
#pragma unroll
    for (int v = 0; v < 2; v++) {
        int idx = v * 256 + t; int r = idx >> 4, c8 = (idx & 15) * 8;
        *(half8*)&h16[((size_t)(g + r) << 7) + c8] = *(const half8*)&otile[r * 136 + c8];
    }
}

// ---------------- adjacency bitmask build: 1024 blocks, 8 rows/wave, pipelined
__global__ __launch_bounds__(256, 8)
void k_mask(const float* __restrict__ adj1, const float* __restrict__ adj2,
            unsigned short* __restrict__ mask16) {
    int t = threadIdx.x, w = t >> 6, l = t & 63;
    int wave = blockIdx.x * 4 + w;
    int R0 = wave * 8;
    int br = R0 >> 14, nb0 = R0 & 16383;
    const float* arow = (br ? adj2 : adj1) + (size_t)nb0 * 1024 + l * 16;
    float4 v0 = *(const float4*)&arow[0];
    float4 v1 = *(const float4*)&arow[4];
    float4 v2 = *(const float4*)&arow[8];
    float4 v3 = *(const float4*)&arow[12];
    unsigned short* mp = mask16 + (size_t)R0 * 64 + l;
#pragma unroll
    for (int it = 0; it < 8; it++) {
        float4 c0 = v0, c1 = v1, c2 = v2, c3 = v3;
        if (it < 7) {
            const float* nx = arow + (size_t)(it + 1) * 1024;
            v0 = *(const float4*)&nx[0];
            v1 = *(const float4*)&nx[4];
            v2 = *(const float4*)&nx[8];
            v3 = *(const float4*)&nx[12];
        }
        unsigned m = 0u;
        m |= (c0.x > 0.f ? 1u : 0u);        m |= (c0.y > 0.f ? 2u : 0u);
        m |= (c0.z > 0.f ? 4u : 0u);        m |= (c0.w > 0.f ? 8u : 0u);
        m |= (c1.x > 0.f ? 0x10u : 0u);     m |= (c1.y > 0.f ? 0x20u : 0u);
        m |= (c1.z > 0.f ? 0x40u : 0u);     m |= (c1.w > 0.f ? 0x80u : 0u);
        m |= (c2.x > 0.f ? 0x100u : 0u);    m |= (c2.y > 0.f ? 0x200u : 0u);
        m |= (c2.z > 0.f ? 0x400u : 0u);    m |= (c2.w > 0.f ? 0x800u : 0u);
        m |= (c3.x > 0.f ? 0x1000u : 0u);   m |= (c3.y > 0.f ? 0x2000u : 0u);
        m |= (c3.z > 0.f ? 0x4000u : 0u);   m |= (c3.w > 0.f ? 0x8000u : 0u);
        mp[it * 64] = (unsigned short)m;
    }
}

// ---------------- proj (MFMA): in = pa - pb (f16); hbr = in@W^T + b ; hS = hbr@S
__global__ __launch_bounds__(256)
void k_proj(const half_t* __restrict__ pa, const half_t* __restrict__ pb,
            const half_t* __restrict__ Wf, const float* __restrict__ bias,
            const half_t* __restrict__ STf,
            half_t* __restrict__ hbr16, half_t* __restrict__ hbrT,
            half_t* __restrict__ hbrF, half_t* __restrict__ hSF) {
    __shared__ half_t htile[32 * 136];
    __shared__ half_t hbtile[32 * 136];
    int g = blockIdx.x * 32;
    int t = threadIdx.x;
    int w = t >> 6, l = t & 63, q = l >> 4, l15 = l & 15;
#pragma unroll
    for (int v = 0; v < 2; v++) {
        int idx = v * 256 + t; int r = idx >> 4, c8 = (idx & 15) * 8;
        half8 va = *(const half8*)&pa[((size_t)(g + r) << 7) + c8];
        if (pb) {
            half8 vb = *(const half8*)&pb[((size_t)(g + r) << 7) + c8];
            va = va - vb;
        }
        *(half8*)&htile[r * 136 + c8] = va;
    }
    __syncthreads();
    int rowh = (w & 1) * 16;
    int c0 = (w >> 1) * 4;
    half8 a1[4];
#pragma unroll
    for (int kc = 0; kc < 4; kc++) a1[kc] = *(const half8*)&htile[(rowh + l15) * 136 + kc * 32 + q * 8];
    floatx4 acc[4];
#pragma unroll
    for (int cc = 0; cc < 4; cc++) {
        int col = (c0 + cc) * 16 + l15;
        floatx4 a = {0.f, 0.f, 0.f, 0.f};
#pragma unroll
        for (int kc = 0; kc < 4; kc++) {
            half8 bf = *(const half8*)&Wf[((size_t)col << 7) + kc * 32 + q * 8];
            a = MFMA(a1[kc], bf, a);
        }
        float bv = bias[col];
        a.x += bv; a.y += bv; a.z += bv; a.w += bv;
        acc[cc] = a;
    }
#pragma unroll
    for (int cc = 0; cc < 4; cc++) {
        int col = (c0 + cc) * 16 + l15;
#pragma unroll
        for (int r = 0; r < 4; r++)
            hbtile[(rowh + q * 4 + r) * 136 + col] = (half_t)acc[cc][r];
    }
    __syncthreads();
    half8 a2[4];
#pragma unroll
    for (int kc = 0; kc < 4; kc++) a2[kc] = *(const half8*)&hbtile[(rowh + l15) * 136 + kc * 32 + q * 8];
#pragma unroll
    for (int cc = 0; cc < 4; cc++) {
        int col = (c0 + cc) * 16 + l15;
        floatx4 a = {0.f, 0.f, 0.f, 0.f};
#pragma unroll
        for (int kc = 0; kc < 4; kc++) {
            half8 bf = *(const half8*)&STf[((size_t)col << 7) + kc * 32 + q * 8];
            a = MFMA(a2[kc], bf, a);
        }
        acc[cc] = a;
    }
    __syncthreads();
#pragma unroll
    for (int cc = 0; cc < 4; cc++) {
        int col = (c0 + cc) * 16 + l15;
#pragma unroll
        for (int r = 0; r < 4; r++) htile[(rowh + q * 4 + r) * 136 + col] = (half_t)acc[cc][r];
    }
    __syncthreads();
#pragma unroll
    for (int v = 0; v < 2; v++) {
        int idx = v * 256 + t; int r = idx >> 4, c8 = (idx & 15) * 8;
        *(half8*)&hbr16[((size_t)(g + r) << 7) + c8] = *(const half8*)&hbtile[r * 136 + c8];
    }
    // transposed hbr: hbrT[b][d][i]
    {
        int b_ = g >> 10, gi = g & 1023;
        int d = t >> 1, hh = t & 1;
        half8 r0, r1;
#pragma unroll
        for (int e = 0; e < 8; e++) {
            r0[e] = hbtile[(hh * 16 + e) * 136 + d];
            r1[e] = hbtile[(hh * 16 + 8 + e) * 136 + d];
        }
        half_t* op = hbrT + ((size_t)b_ * 128 + d) * 1024 + gi + hh * 16;
        *(half8*)op = r0;
        *(half8*)(op + 8) = r1;
    }
#pragma unroll
    for (int v = 0; v < 2; v++) {
        int fi = v * 256 + t;
        int g2 = fi >> 8, kc = (fi >> 6) & 3, li = fi & 63;
        int src = (g2 * 16 + (li & 15)) * 136 + kc * 32 + (li >> 4) * 8;
        size_t dst = (((size_t)(blockIdx.x * 2 + g2) * 4 + kc) << 10) + li * 8;
        *(half8*)&hbrF[dst] = *(const half8*)&hbtile[src];
        *(half8*)&hSF[dst]  = *(const half8*)&htile[src];
    }
}

// ---------------- E slim: em strip (MFMA) -> rowsums -> rsr + hbrsT. NO Dm.
__global__ __launch_bounds__(256)
void k_E(const half_t* __restrict__ hSF, const half_t* __restrict__ hbrF,
         const unsigned short* __restrict__ mask16, const half_t* __restrict__ hbrT,
         float* __restrict__ rsr, half_t* __restrict__ hbrsT) {
    int hw = blockIdx.y * 64 + blockIdx.x;
    int wk = (hw & 7) * 128 + (hw >> 3);
    int b = wk >> 6, s = wk & 63;              // 64 strips of 16 rows per batch
    int t = threadIdx.x, w = t >> 6, l = t & 63, q = l >> 4, l15 = l & 15;
    __shared__ half_t emS[16 * EMP];
    __shared__ float rsS[2][16];
    size_t Gb = (size_t)b * 64;
    half8 A[4];
#pragma unroll
    for (int kc = 0; kc < 4; kc++)
        A[kc] = *(const half8*)&hSF[(((Gb + s) * 4 + kc) << 10) + l * 8];
#pragma unroll 4
    for (int cg = 0; cg < 16; cg++) {
        int c0 = w * 256 + cg * 16;
        floatx4 a = {0.f, 0.f, 0.f, 0.f};
#pragma unroll
        for (int kc = 0; kc < 4; kc++) {
            half8 bf = *(const half8*)&hbrF[(((Gb + w * 16 + cg) * 4 + kc) << 10) + l * 8];
            a = MFMA(A[kc], bf, a);
        }
#pragma unroll
        for (int r = 0; r < 4; r++)
            emS[(q * 4 + r) * EMP + c0 + l15] = (half_t)a[r];
    }
    __syncthreads();
    const float CN = 0.000335462627903f;       // exp(-8)
#pragma unroll
    for (int tt = 0; tt < 8; tt++) {
        int task = tt * 4 + w;                 // 32 tasks: (rl, br)
        int rl = task >> 1, br = task & 1;
        size_t R = ((size_t)br << 14) + (size_t)b * 1024 + s * 16 + rl;
        unsigned mv = (unsigned)mask16[R * 64 + l];
        half8 e0 = *(const half8*)&emS[rl * EMP + l * 16];
        half8 e1 = *(const half8*)&emS[rl * EMP + l * 16 + 8];
        float rs = 0.f;
#pragma unroll
        for (int c2 = 0; c2 < 8; c2++) {
            float v0 = ((mv >> c2) & 1u) ? __expf((float)e0[c2] - 8.f) : 0.f;
            float v1 = ((mv >> (c2 + 8)) & 1u) ? __expf((float)e1[c2] - 8.f) : 0.f;
            rs += v0 + v1;
        }
        int cn = __popc(mv);
        rs += __shfl_xor(rs, 1); rs += __shfl_xor(rs, 2);
        rs += __shfl_xor(rs, 4); rs += __shfl_xor(rs, 8);
        rs += __shfl_xor(rs, 16); rs += __shfl_xor(rs, 32);
        cn += __shfl_xor(cn, 1); cn += __shfl_xor(cn, 2);
        cn += __shfl_xor(cn, 4); cn += __shfl_xor(cn, 8);
        cn += __shfl_xor(cn, 16); cn += __shfl_xor(cn, 32);
        if (l == 0) {
            float rv = 1.f / (rs + (1024.f - (float)cn) * CN);
            rsr[R] = rv;
            rsS[br][rl] = rv;
        }
    }
    __syncthreads();
    // hbrsT[(br,b)][d][i] = rsr[i] * hbrT[b][d][i]
    {
        int d = t >> 1, br = t & 1;
        const half_t* hp = hbrT + ((size_t)b * 128 + d) * 1024 + s * 16;
        half8 a0 = *(const half8*)hp, a1 = *(const half8*)(hp + 8);
        half8 r0, r1;
#pragma unroll
        for (int e = 0; e < 8; e++) {
            r0[e] = (half_t)((float)a0[e] * rsS[br][e]);
            r1[e] = (half_t)((float)a1[e] * rsS[br][8 + e]);
        }
        half_t* op = hbrsT + (((size_t)((br << 4) + b)) * 128 + d) * 1024 + s * 16;
        *(half8*)op = r0;
        *(half8*)(op + 8) = r1;
    }
}

// ---------------- FUSED az (flash-style): per block = (slice, 128-i tile).
// Loop over 8 j-blocks of 128: recompute em = hS.hbr^T (MFMA, LDS-staged
// fragments), mask+exp -> P (LDS), PV az += P @ z (z staged fragment-order).
// No dense D in global memory. Epilogue identical math to previous k_azd.
__global__ __launch_bounds__(512)
void k_azf(const half_t* __restrict__ hSF, const half_t* __restrict__ hbrF,
           const unsigned short* __restrict__ mask16, const float* __restrict__ rsr,
           const half_t* __restrict__ BT, const half_t* __restrict__ hbr16,
           const float* __restrict__ gw, const float* __restrict__ gb_,
           float* __restrict__ cfb, half_t* __restrict__ outR, half_t* __restrict__ outT,
           int mode) {
    __shared__ unsigned short maskL[128][64];          // 16 KB
    __shared__ union {
        half_t hb[32768];                              // 64 KB: hbrF j-block frags
        struct { half_t P[128 * 136]; half_t zf[16384]; } pv;  // 34.8 + 32 KB
    } sm;
    int t = threadIdx.x, w = t >> 6, l = t & 63, q = l >> 4, l15 = l & 15;
    int bid = blockIdx.x;
    int slice = bid & 31, tile = bid >> 5;             // slice pinned to XCD slice%8
    int br = slice & 1, b = slice >> 1;
    int c = (br << 4) + b;
    int i0 = tile * 128;
    // stage mask rows for this i-tile
    {
        const uint4* src = (const uint4*)(mask16 + ((size_t)c * 1024 + i0) * 64);
        uint4* dst = (uint4*)&maskL[0][0];
        dst[t] = src[t];
        dst[t + 512] = src[t + 512];
    }
    // persistent S A-frags: wave w's 16-row i-strip
    half8 As[4];
    size_t stripg = (size_t)b * 64 + tile * 8 + w;
#pragma unroll
    for (int kc = 0; kc < 4; kc++)
        As[kc] = *(const half8*)&hSF[((stripg * 4 + kc) << 10) + l * 8];
    floatx4 accp[8] = {};                              // az[16 i][128 d]
    const half_t* zsrc = BT + ((size_t)c << 17);
    const half_t* hbsrc = hbrF + (((size_t)b * 256) << 10);
    __syncthreads();
    for (int jb = 0; jb < 8; jb++) {
        // stage hbrF j-block (contiguous 64 KB of fragment slots)
        {
            const half8* s8 = (const half8*)(hbsrc + ((size_t)jb * 32 << 10));
            half8* d8 = (half8*)sm.hb;
#pragma unroll
            for (int rep = 0; rep < 8; rep++)
                d8[rep * 512 + t] = s8[rep * 512 + t];
        }
        __syncthreads();
        // S-GEMM: em[16 i][128 j] for this wave
        floatx4 as[8];
#pragma unroll
        for (int cg = 0; cg < 8; cg++) {
            floatx4 a = {0.f, 0.f, 0.f, 0.f};
#pragma unroll
            for (int kc = 0; kc < 4; kc++) {
                half8 bf = *(const half8*)&sm.hb[((cg * 4 + kc) << 10) + l * 8];
                a = MFMA(As[kc], bf, a);
            }
            as[cg] = a;
        }
        __syncthreads();                               // hb reads done
        // mask + exp -> P[128][136]
#pragma unroll
        for (int cg = 0; cg < 8; cg++) {
#pragma unroll
            for (int r = 0; r < 4; r++) {
                int il = w * 16 + q * 4 + r;
                unsigned mv = (unsigned)maskL[il][jb * 8 + cg];
                float v = ((mv >> l15) & 1u) ? __expf(as[cg][r] - 8.f) : 0.f;
                sm.pv.P[il * 136 + cg * 16 + l15] = (half_t)v;
            }
        }
        // stage z j-block into B-fragment order zf[(g*4+kc)*512 + li*8]
#pragma unroll
        for (int rep = 0; rep < 4; rep++) {
            int chunk = rep * 512 + t;
            int d = chunk >> 4, x = chunk & 15;
            half8 v = *(const half8*)&zsrc[(size_t)d * 1024 + jb * 128 + x * 8];
            int li = ((x & 3) << 4) | (d & 15);
            *(half8*)&sm.pv.zf[(((d >> 4) * 4 + (x >> 2)) << 9) + li * 8] = v;
        }
        __syncthreads();
        // PV: az[16 i][128 d] += P_strip @ z  (K = 128 j, 4 kc)
#pragma unroll
        for (int kc = 0; kc < 4; kc++) {
            half8 af = *(const half8*)&sm.pv.P[(w * 16 + l15) * 136 + kc * 32 + q * 8];
#pragma unroll
            for (int cg = 0; cg < 8; cg++) {
                half8 bf = *(const half8*)&sm.pv.zf[((cg * 4 + kc) << 9) + l * 8];
                accp[cg] = MFMA(af, bf, accp[cg]);
            }
        }
        __syncthreads();
    }
    // accp -> az tile (reuse P region)
#pragma unroll
    for (int cg = 0; cg < 8; cg++)
#pragma unroll
        for (int r = 0; r < 4; r++)
            sm.pv.P[(w * 16 + q * 4 + r) * 136 + cg * 16 + l15] = (half_t)accp[cg][r];
    __syncthreads();
#pragma unroll
    for (int it = 0; it < 4; it++) {
        int iloc = it * 32 + (t >> 4);
        int i = i0 + iloc;
        int nb = b * 1024 + i;
        int R = c * 1024 + i;
        half8 az8 = *(const half8*)&sm.pv.P[iloc * 136 + l15 * 8];
        half8 hv8 = *(const half8*)&hbr16[((size_t)nb << 7) + l15 * 8];
        float av[8], hv[8];
#pragma unroll
        for (int d = 0; d < 8; d++) {
            av[d] = fmaxf((float)az8[d], 0.f);
            hv[d] = (float)hv8[d];
        }
        float cf;
        if (mode >= 3) {
            const float* g1 = gw + l15 * 8;
            const float* g2 = gw + 128 + l15 * 8;
            float dp = 0.f;
#pragma unroll
            for (int d = 0; d < 8; d++) dp += hv[d] * g1[d] + av[d] * g2[d];
            dp += __shfl_xor(dp, 1); dp += __shfl_xor(dp, 2);
            dp += __shfl_xor(dp, 4); dp += __shfl_xor(dp, 8);
            cf = 1.f / (1.f + __expf(-(dp + gb_[0])));
            if (l15 == 0) cfb[R] = cf;
        } else {
            cf = cfb[R];
        }
        if (mode == 2 || mode == 4) {
            half8 o;
#pragma unroll
            for (int d = 0; d < 8; d++) o[d] = (half_t)(cf * hv[d] + (1.f - cf) * av[d]);
            *(half8*)&outR[(size_t)R * DD + l15 * 8] = o;
        } else {
            float sc = rsr[R];
#pragma unroll
            for (int d = 0; d < 8; d++)
                sm.pv.P[iloc * 136 + l15 * 8 + d] = (half_t)(sc * (cf * hv[d] + (1.f - cf) * av[d]));
        }
    }
    if (mode == 1 || mode == 3) {
        __syncthreads();
        int d = t & 127, g4 = t >> 7;
        half_t* op = outT + ((size_t)c * 128 + d) * 1024 + i0 + g4 * 32;
        half8 r0, r1, r2, r3;
#pragma unroll
        for (int e = 0; e < 8; e++) {
            r0[e] = sm.pv.P[(g4 * 32 + e) * 136 + d];
            r1[e] = sm.pv.P[(g4 * 32 + 8 + e) * 136 + d];
            r2[e] = sm.pv.P[(g4 * 32 + 16 + e) * 136 + d];
            r3[e] = sm.pv.P[(g4 * 32 + 24 + e) * 136 + d];
        }
        *(half8*)op = r0;
        *(half8*)(op + 8) = r1;
        *(half8*)(op + 16) = r2;
        *(half8*)(op + 24) = r3;
    }
}

// ---------------- partial masked pool of (z2 - z1), f16 inputs
__global__ __launch_bounds__(256)
void k_pool(const half_t* __restrict__ z2, const half_t* __restrict__ z1,
            const float* __restrict__ valid, float* __restrict__ part) {
    int b = blockIdx.y, s = blockIdx.x;
    int t = threadIdx.x, d = t & 127, hf = t >> 7;
    __shared__ float red[128];
    float acc = 0.f;
    int nbase = s * 128 + hf * 64;
    for (int n = nbase; n < nbase + 64; n++) {
        size_t gi = ((size_t)(b * 1024 + n) << 7) + d;
        acc += ((float)z2[gi] - (float)z1[gi]) * valid[b * 1024 + n];
    }
    if (hf) red[d] = acc;
    __syncthreads();
    if (!hf) part[(b * 8 + s) * 128 + d] = acc + red[d];
}

// ---------------- final reduce + MLP head
__global__ __launch_bounds__(128)
void k_mlp(const float* __restrict__ part, const float* __restrict__ valid,
           const float* __restrict__ w0, const float* __restrict__ b0,
           const float* __restrict__ w1, const float* __restrict__ b1,
           const float* __restrict__ w2, const float* __restrict__ b2,
           const float* __restrict__ w3, const float* __restrict__ b3,
           float* __restrict__ out) {
    int b = blockIdx.x, t = threadIdx.x;
    __shared__ float y0[DD], y1[DD];
    __shared__ float sred[2];
    float vs = 0.f;
    for (int n = t; n < NLEN; n += 128) vs += valid[b * NLEN + n];
    for (int off = 32; off; off >>= 1) vs += __shfl_down(vs, off);
    if ((t & 63) == 0) sred[t >> 6] = vs;
    __syncthreads();
    float vsum = sred[0] + sred[1];
    float acc = 0.f;
#pragma unroll
    for (int s = 0; s < 8; s++) acc += part[(b * 8 + s) * 128 + t];
    y0[t] = acc / vsum;
    __syncthreads();
    float a = b0[t];
    for (int k = 0; k < DD; k++) a += y0[k] * w0[t * DD + k];
    y1[t] = fmaxf(a, 0.f);
    __syncthreads();
    a = b1[t];
    for (int k = 0; k < DD; k++) a += y1[k] * w1[t * DD + k];
    y0[t] = fmaxf(a, 0.f);
    __syncthreads();
    a = b2[t];
    for (int k = 0; k < DD; k++) a += y0[k] * w2[t * DD + k];
    y1[t] = fmaxf(a, 0.f);
    __syncthreads();
    float pv = y1[t] * w3[t];
    for (int off = 32; off; off >>= 1) pv += __shfl_down(pv, off);
    if ((t & 63) == 0) sred[t >> 6] = pv;
    __syncthreads();
    if (t == 0) out[b] = 1.f / (1.f + __expf(-(sred[0] + sred[1] + b3[0])));
}

extern "C" void kernel_launch(void* const* d_in, const int* in_sizes, int n_in,
                              void* d_out, int out_size, void* d_ws, size_t ws_size,
                              hipStream_t stream) {
    (void)in_sizes; (void)n_in; (void)out_size; (void)ws_size;
    const float* x     = (const float*)d_in[0];
    const float* adj1  = (const float*)d_in[1];
    const float* adj2  = (const float*)d_in[2];
    const float* valid = (const float*)d_in[3];
    const float* Ew    = (const float*)d_in[4];
    const float* gW    = (const float*)d_in[5];
    const float* gb    = (const float*)d_in[6];
    const float* gA    = (const float*)d_in[7];
    const float* gatew = (const float*)d_in[8];
    const float* gateb = (const float*)d_in[9];
    const float* w0 = (const float*)d_in[10]; const float* b0 = (const float*)d_in[11];
    const float* w1 = (const float*)d_in[12]; const float* b1 = (const float*)d_in[13];
    const float* w2 = (const float*)d_in[14]; const float* b2 = (const float*)d_in[15];
    const float* w3 = (const float*)d_in[16]; const float* b3 = (const float*)d_in[17];
    float* out = (float*)d_out;

    char* p = (char*)d_ws;
    float* rsr  = (float*)p; p += 2 * BN * 4;
    float* cfb  = (float*)p; p += 2 * BN * 4;
    float* partb = (float*)p; p += (size_t)NB * 8 * 128 * 4;
    half_t* h16   = (half_t*)p; p += BND * 2;
    half_t* hbr16 = (half_t*)p; p += BND * 2;
    half_t* hbrF  = (half_t*)p; p += BND * 2;
    half_t* hSF   = (half_t*)p; p += BND * 2;
    half_t* hbrT  = (half_t*)p; p += BND * 2;       // [16 b][128 d][1024 i]
    half_t* hbrsT = (half_t*)p; p += 2 * BND * 2;   // [(br,b)][128 d][1024 i]
    half_t* zf    = (half_t*)p; p += 2 * BND * 2;   // layer outputs, row-major
    half_t* zTA   = (half_t*)p; p += 2 * BND * 2;   // hop buffers, transposed
    half_t* zTB   = (half_t*)p; p += 2 * BND * 2;
    unsigned short* mask16 = (unsigned short*)p; p += (size_t)2 * BN * 64 * 2;
    half_t* Wf16 = (half_t*)p; p += (size_t)4 * 128 * 128 * 2;
    half_t* ST16 = (half_t*)p; p += (size_t)4 * 128 * 128 * 2;
    half_t* EwF  = (half_t*)p; p += (size_t)128 * 128 * 2;

    k_cast<<<320, 256, 0, stream>>>(gW, gA, Ew, Wf16, ST16, EwF);
    k_emb<<<512, 256, 0, stream>>>(x, EwF, h16);
    k_mask<<<1024, 256, 0, stream>>>(adj1, adj2, mask16);

    for (int k = 0; k < 4; k++) {
        int nhop = k + 1;
        const half_t* pa = k ? (zf + BND) : h16;
        const half_t* pb = k ? zf : nullptr;
        k_proj<<<512, 256, 0, stream>>>(pa, pb, Wf16 + (size_t)k * 16384, gb + k * 128,
                                        ST16 + (size_t)k * 16384, hbr16, hbrT, hbrF, hSF);
        k_E<<<dim3(64, NB), 256, 0, stream>>>(hSF, hbrF, mask16, hbrT, rsr, hbrsT);
        // hop 1 (gate computed in-kernel)
        if (nhop == 1) {
            k_azf<<<256, 512, 0, stream>>>(hSF, hbrF, mask16, rsr, hbrsT, hbr16,
                                           gatew + k * 256, gateb + k, cfb,
                                           zf, (half_t*)nullptr, 4);
        } else {
            k_azf<<<256, 512, 0, stream>>>(hSF, hbrF, mask16, rsr, hbrsT, hbr16,
                                           gatew + k * 256, gateb + k, cfb,
                                           (half_t*)nullptr, zTA, 3);
        }
        const half_t* srcT = zTA;
        for (int hop = 2; hop <= nhop; hop++) {
            if (hop == nhop) {
                k_azf<<<256, 512, 0, stream>>>(hSF, hbrF, mask16, rsr, srcT, hbr16,
                                               gatew + k * 256, gateb + k, cfb,
                                               zf, (half_t*)nullptr, 2);
            } else {
                half_t* dT = (hop & 1) ? zTA : zTB;
                k_azf<<<256, 512, 0, stream>>>(hSF, hbrF, mask16, rsr, srcT, hbr16,
                                               gatew + k * 256, gateb + k, cfb,
                                               (half_t*)nullptr, dT, 1);
                srcT = dT;
            }
        }
    }
    k_pool<<<dim3(8, NB), 256, 0, stream>>>(zf + BND, zf, valid, partb);
    k_mlp<<<16, 128, 0, stream>>>(partb, valid, w0, b0, w1, b1, w2, b2, w3, b3, out);
}

// Round 11
// 621.394 us; speedup vs baseline: 1.2899x; 1.2899x over previous
//
#include <hip/hip_runtime.h>

typedef _Float16 half_t;
typedef _Float16 half8 __attribute__((ext_vector_type(8)));
typedef float floatx4 __attribute__((ext_vector_type(4)));

#define MFMA(a,b,c) __builtin_amdgcn_mfma_f32_16x16x32_f16(a,b,c,0,0,0)

#define NB 16
#define NLEN 1024
#define DD 128
#define BN (NB*NLEN)                       // 16384 rows per branch
#define BND ((size_t)NB*NLEN*DD)
#define EMP 1044                           // emS row stride

// ---------------- weight casts: gW->Wf16, gA+gA^T->ST16, Ew->EwF
__global__ __launch_bounds__(256)
void k_cast(const float* __restrict__ gW, const float* __restrict__ gA,
            const float* __restrict__ Ew,
            half_t* __restrict__ Wf, half_t* __restrict__ STf, half_t* __restrict__ EwF) {
    int i = blockIdx.x * 256 + threadIdx.x;
    if (i < 65536) {
        Wf[i] = (half_t)gW[i];
        int base = i & ~16383;
        int lrem = i & 16383;
        int d = lrem >> 7, e = lrem & 127;
        STf[base + (e << 7) + d] = (half_t)(gA[i] + gA[base + (e << 7) + d]);
    } else {
        int j = i - 65536;
        EwF[j] = (half_t)Ew[j];
    }
}

// ---------------- embed as MFMA GEMM: h16 = f16(x) @ EwF^T
__global__ __launch_bounds__(256)
void k_emb(const float* __restrict__ x, const half_t* __restrict__ EwF,
           half_t* __restrict__ h16) {
    __shared__ half_t htile[32 * 136];
    __shared__ half_t otile[32 * 136];
    int g = blockIdx.x * 32;
    int t = threadIdx.x;
    int w = t >> 6, l = t & 63, q = l >> 4, l15 = l & 15;
#pragma unroll
    for (int v = 0; v < 2; v++) {
        int idx = v * 256 + t; int r = idx >> 4, c8 = (idx & 15) * 8;
        const float* xp = &x[(size_t)(g + r) * DD + c8];
        float4 f0 = *(const float4*)xp;
        float4 f1 = *(const float4*)(xp + 4);
        half8 va;
        va[0] = (half_t)f0.x; va[1] = (half_t)f0.y; va[2] = (half_t)f0.z; va[3] = (half_t)f0.w;
        va[4] = (half_t)f1.x; va[5] = (half_t)f1.y; va[6] = (half_t)f1.z; va[7] = (half_t)f1.w;
        *(half8*)&htile[r * 136 + c8] = va;
    }
    __syncthreads();
    int rowh = (w & 1) * 16;
    int c0 = (w >> 1) * 4;
    half8 a1[4];
#pragma unroll
    for (int kc = 0; kc < 4; kc++) a1[kc] = *(const half8*)&htile[(rowh + l15) * 136 + kc * 32 + q * 8];
#pragma unroll
    for (int cc = 0; cc < 4; cc++) {
        int col = (c0 + cc) * 16 + l15;
        floatx4 a = {0.f, 0.f, 0.f, 0.f};
#pragma unroll
        for (int kc = 0; kc < 4; kc++) {
            half8 bf = *(const half8*)&EwF[((size_t)col << 7) + kc * 32 + q * 8];
            a = MFMA(a1[kc], bf, a);
        }
#pragma unroll
        for (int r = 0; r < 4; r++)
            otile[(rowh + q * 4 + r) * 136 + col] = (half_t)a[r];
    }
    __syncthreads();
#pragma unroll
    for (int v = 0; v < 2; v++) {
        int idx = v * 256 + t; int r = idx >> 4, c8 = (idx & 15) * 8;
        *(half8*)&h16[((size_t)(g + r) << 7) + c8] = *(const half8*)&otile[r * 136 + c8];
    }
}

// ---------------- adjacency bitmask build, coalesced via LDS bounce (round-8 best)
__global__ __launch_bounds__(256)
void k_mask(const float* __restrict__ adj1, const float* __restrict__ adj2,
            unsigned short* __restrict__ mask16) {
    __shared__ float ls[4][1024];              // 16 KiB
    int tid = threadIdx.x;
    int bid = blockIdx.x;
    int w = tid >> 6, l = tid & 63;
    int R = bid * 4 + w;
    int br = R >> 14, nb = R & 16383;
    const float* arow = (br ? adj2 : adj1) + (size_t)nb * 1024;
#pragma unroll
    for (int c = 0; c < 4; c++)
        *(float4*)&ls[w][c * 256 + l * 4] = *(const float4*)&arow[c * 256 + l * 4];
    __syncthreads();
    unsigned m = 0u;
#pragma unroll
    for (int c = 0; c < 4; c++) {
        float4 v = *(const float4*)&ls[w][l * 16 + c * 4];
        m |= (v.x > 0.f ? 1u : 0u) << (c * 4);
        m |= (v.y > 0.f ? 1u : 0u) << (c * 4 + 1);
        m |= (v.z > 0.f ? 1u : 0u) << (c * 4 + 2);
        m |= (v.w > 0.f ? 1u : 0u) << (c * 4 + 3);
    }
    mask16[(size_t)R * 64 + l] = (unsigned short)m;
}

// ---------------- proj (MFMA): in = pa - pb (f16); hbr = in@W^T + b ; hS = hbr@S
__global__ __launch_bounds__(256)
void k_proj(const half_t* __restrict__ pa, const half_t* __restrict__ pb,
            const half_t* __restrict__ Wf, const float* __restrict__ bias,
            const half_t* __restrict__ STf,
            half_t* __restrict__ hbr16, half_t* __restrict__ hbrT,
            half_t* __restrict__ hbrF, half_t* __restrict__ hSF) {
    __shared__ half_t htile[32 * 136];
    __shared__ half_t hbtile[32 * 136];
    int g = blockIdx.x * 32;
    int t = threadIdx.x;
    int w = t >> 6, l = t & 63, q = l >> 4, l15 = l & 15;
#pragma unroll
    for (int v = 0; v < 2; v++) {
        int idx = v * 256 + t; int r = idx >> 4, c8 = (idx & 15) * 8;
        half8 va = *(const half8*)&pa[((size_t)(g + r) << 7) + c8];
        if (pb) {
            half8 vb = *(const half8*)&pb[((size_t)(g + r) << 7) + c8];
            va = va - vb;
        }
        *(half8*)&htile[r * 136 + c8] = va;
    }
    __syncthreads();
    int rowh = (w & 1) * 16;
    int c0 = (w >> 1) * 4;
    half8 a1[4];
#pragma unroll
    for (int kc = 0; kc < 4; kc++) a1[kc] = *(const half8*)&htile[(rowh + l15) * 136 + kc * 32 + q * 8];
    floatx4 acc[4];
#pragma unroll
    for (int cc = 0; cc < 4; cc++) {
        int col = (c0 + cc) * 16 + l15;
        floatx4 a = {0.f, 0.f, 0.f, 0.f};
#pragma unroll
        for (int kc = 0; kc < 4; kc++) {
            half8 bf = *(const half8*)&Wf[((size_t)col << 7) + kc * 32 + q * 8];
            a = MFMA(a1[kc], bf, a);
        }
        float bv = bias[col];
        a.x += bv; a.y += bv; a.z += bv; a.w += bv;
        acc[cc] = a;
    }
#pragma unroll
    for (int cc = 0; cc < 4; cc++) {
        int col = (c0 + cc) * 16 + l15;
#pragma unroll
        for (int r = 0; r < 4; r++)
            hbtile[(rowh + q * 4 + r) * 136 + col] = (half_t)acc[cc][r];
    }
    __syncthreads();
    half8 a2[4];
#pragma unroll
    for (int kc = 0; kc < 4; kc++) a2[kc] = *(const half8*)&hbtile[(rowh + l15) * 136 + kc * 32 + q * 8];
#pragma unroll
    for (int cc = 0; cc < 4; cc++) {
        int col = (c0 + cc) * 16 + l15;
        floatx4 a = {0.f, 0.f, 0.f, 0.f};
#pragma unroll
        for (int kc = 0; kc < 4; kc++) {
            half8 bf = *(const half8*)&STf[((size_t)col << 7) + kc * 32 + q * 8];
            a = MFMA(a2[kc], bf, a);
        }
        acc[cc] = a;
    }
    __syncthreads();
#pragma unroll
    for (int cc = 0; cc < 4; cc++) {
        int col = (c0 + cc) * 16 + l15;
#pragma unroll
        for (int r = 0; r < 4; r++) htile[(rowh + q * 4 + r) * 136 + col] = (half_t)acc[cc][r];
    }
    __syncthreads();
#pragma unroll
    for (int v = 0; v < 2; v++) {
        int idx = v * 256 + t; int r = idx >> 4, c8 = (idx & 15) * 8;
        *(half8*)&hbr16[((size_t)(g + r) << 7) + c8] = *(const half8*)&hbtile[r * 136 + c8];
    }
    // transposed hbr: hbrT[b][d][i]
    {
        int b_ = g >> 10, gi = g & 1023;
        int d = t >> 1, hh = t & 1;
        half8 r0, r1;
#pragma unroll
        for (int e = 0; e < 8; e++) {
            r0[e] = hbtile[(hh * 16 + e) * 136 + d];
            r1[e] = hbtile[(hh * 16 + 8 + e) * 136 + d];
        }
        half_t* op = hbrT + ((size_t)b_ * 128 + d) * 1024 + gi + hh * 16;
        *(half8*)op = r0;
        *(half8*)(op + 8) = r1;
    }
#pragma unroll
    for (int v = 0; v < 2; v++) {
        int fi = v * 256 + t;
        int g2 = fi >> 8, kc = (fi >> 6) & 3, li = fi & 63;
        int src = (g2 * 16 + (li & 15)) * 136 + kc * 32 + (li >> 4) * 8;
        size_t dst = (((size_t)(blockIdx.x * 2 + g2) * 4 + kc) << 10) + li * 8;
        *(half8*)&hbrF[dst] = *(const half8*)&hbtile[src];
        *(half8*)&hSF[dst]  = *(const half8*)&htile[src];
    }
}

// ---------------- E: em strip (MFMA) -> DENSE D rows (mask?exp:0), rsr, hbrsT.
__global__ __launch_bounds__(256)
void k_E(const half_t* __restrict__ hSF, const half_t* __restrict__ hbrF,
         const unsigned short* __restrict__ mask16, const half_t* __restrict__ hbrT,
         half_t* __restrict__ Dm, float* __restrict__ rsr, half_t* __restrict__ hbrsT) {
    int hw = blockIdx.y * 64 + blockIdx.x;
    int wk = (hw & 7) * 128 + (hw >> 3);
    int b = wk >> 6, s = wk & 63;              // 64 strips of 16 rows per batch
    int t = threadIdx.x, w = t >> 6, l = t & 63, q = l >> 4, l15 = l & 15;
    __shared__ half_t emS[16 * EMP];
    __shared__ float rsS[2][16];
    size_t Gb = (size_t)b * 64;
    half8 A[4];
#pragma unroll
    for (int kc = 0; kc < 4; kc++)
        A[kc] = *(const half8*)&hSF[(((Gb + s) * 4 + kc) << 10) + l * 8];
#pragma unroll 4
    for (int cg = 0; cg < 16; cg++) {
        int c0 = w * 256 + cg * 16;
        floatx4 a = {0.f, 0.f, 0.f, 0.f};
#pragma unroll
        for (int kc = 0; kc < 4; kc++) {
            half8 bf = *(const half8*)&hbrF[(((Gb + w * 16 + cg) * 4 + kc) << 10) + l * 8];
            a = MFMA(A[kc], bf, a);
        }
#pragma unroll
        for (int r = 0; r < 4; r++)
            emS[(q * 4 + r) * EMP + c0 + l15] = (half_t)a[r];
    }
    __syncthreads();
    const float CN = 0.000335462627903f;       // exp(-8)
#pragma unroll
    for (int tt = 0; tt < 8; tt++) {
        int task = tt * 4 + w;                 // 32 tasks: (rl, br)
        int rl = task >> 1, br = task & 1;
        size_t R = ((size_t)br << 14) + (size_t)b * 1024 + s * 16 + rl;
        unsigned mv = (unsigned)mask16[R * 64 + l];
        half8 e0 = *(const half8*)&emS[rl * EMP + l * 16];
        half8 e1 = *(const half8*)&emS[rl * EMP + l * 16 + 8];
        half8 o0, o1;
        float rs = 0.f;
#pragma unroll
        for (int c2 = 0; c2 < 8; c2++) {
            float v0 = ((mv >> c2) & 1u) ? __expf((float)e0[c2] - 8.f) : 0.f;
            float v1 = ((mv >> (c2 + 8)) & 1u) ? __expf((float)e1[c2] - 8.f) : 0.f;
            o0[c2] = (half_t)v0; o1[c2] = (half_t)v1;
            rs += v0 + v1;
        }
        *(half8*)&Dm[R * 1024 + l * 16] = o0;
        *(half8*)&Dm[R * 1024 + l * 16 + 8] = o1;
        int cn = __popc(mv);
        rs += __shfl_xor(rs, 1); rs += __shfl_xor(rs, 2);
        rs += __shfl_xor(rs, 4); rs += __shfl_xor(rs, 8);
        rs += __shfl_xor(rs, 16); rs += __shfl_xor(rs, 32);
        cn += __shfl_xor(cn, 1); cn += __shfl_xor(cn, 2);
        cn += __shfl_xor(cn, 4); cn += __shfl_xor(cn, 8);
        cn += __shfl_xor(cn, 16); cn += __shfl_xor(cn, 32);
        if (l == 0) {
            float rv = 1.f / (rs + (1024.f - (float)cn) * CN);
            rsr[R] = rv;
            rsS[br][rl] = rv;
        }
    }
    __syncthreads();
    // hbrsT[(br,b)][d][i] = rsr[i] * hbrT[b][d][i]
    {
        int d = t >> 1, br = t & 1;
        const half_t* hp = hbrT + ((size_t)b * 128 + d) * 1024 + s * 16;
        half8 a0 = *(const half8*)hp, a1 = *(const half8*)(hp + 8);
        half8 r0, r1;
#pragma unroll
        for (int e = 0; e < 8; e++) {
            r0[e] = (half_t)((float)a0[e] * rsS[br][e]);
            r1[e] = (half_t)((float)a1[e] * rsS[br][8 + e]);
        }
        half_t* op = hbrsT + (((size_t)((br << 4) + b)) * 128 + d) * 1024 + s * 16;
        *(half8*)op = r0;
        *(half8*)(op + 8) = r1;
    }
}

// ---------------- dense az GEMM, staged (§5) — BM=64 for 2 blocks/CU:
// grid 512 = 32 slices x 16 M-tiles of 64 rows (slice = bid&31 -> one XCD).
// Block: 512 thr (8 waves), BN=128, BK=64, double-buffered LDS (54 KB ->
// 2 blocks/CU = cross-block overlap hides barrier drains). Wave = 16i x 64d.
__global__ __launch_bounds__(512)
void k_azd(const half_t* __restrict__ Dm, const float* __restrict__ rsr,
           const half_t* __restrict__ BT, const half_t* __restrict__ hbr16,
           const float* __restrict__ gw, const float* __restrict__ gb_,
           float* __restrict__ cfb, half_t* __restrict__ outR, half_t* __restrict__ outT,
           int mode) {
    __shared__ union {
        struct { half_t A[2][64][72]; half_t B[2][128][72]; } s;
        half_t az[64][136];
    } sm;
    int t = threadIdx.x, w = t >> 6, l = t & 63, q = l >> 4, l15 = l & 15;
    int wi = w & 3, wd = w >> 2;               // i-group (16 rows) / d-half (64)
    int bid = blockIdx.x;
    int slice = bid & 31, tile = bid >> 5;     // 16 tiles of 64 rows
    int br = slice & 1, b = slice >> 1;
    int c = (br << 4) + b;
    int i0 = tile * 64;
    const half_t* Dp = Dm + ((size_t)c << 20) + (size_t)i0 * 1024;
    const half_t* Bp = BT + ((size_t)c << 17);
    int ar = t >> 3, ac = (t & 7) * 8;         // staging coords
    half8 ra0, rb0, rb1;
    ra0 = *(const half8*)&Dp[(size_t)ar * 1024 + ac];
    rb0 = *(const half8*)&Bp[(size_t)ar * 1024 + ac];
    rb1 = *(const half8*)&Bp[(size_t)(ar + 64) * 1024 + ac];
    *(half8*)&sm.s.A[0][ar][ac] = ra0;
    *(half8*)&sm.s.B[0][ar][ac] = rb0;
    *(half8*)&sm.s.B[0][ar + 64][ac] = rb1;
    __syncthreads();
    floatx4 acc[4] = {};
    for (int kt = 0; kt < 16; kt++) {
        int buf = kt & 1;
        if (kt < 15) {
            int ko = (kt + 1) * 64;
            ra0 = *(const half8*)&Dp[(size_t)ar * 1024 + ko + ac];
            rb0 = *(const half8*)&Bp[(size_t)ar * 1024 + ko + ac];
            rb1 = *(const half8*)&Bp[(size_t)(ar + 64) * 1024 + ko + ac];
        }
#pragma unroll
        for (int kk = 0; kk < 2; kk++) {
            half8 af = *(const half8*)&sm.s.A[buf][wi * 16 + l15][kk * 32 + q * 8];
#pragma unroll
            for (int nf = 0; nf < 4; nf++) {
                half8 bf = *(const half8*)&sm.s.B[buf][wd * 64 + nf * 16 + l15][kk * 32 + q * 8];
                acc[nf] = MFMA(af, bf, acc[nf]);
            }
        }
        __syncthreads();
        if (kt < 15) {
            int nbuf = buf ^ 1;
            *(half8*)&sm.s.A[nbuf][ar][ac] = ra0;
            *(half8*)&sm.s.B[nbuf][ar][ac] = rb0;
            *(half8*)&sm.s.B[nbuf][ar + 64][ac] = rb1;
            __syncthreads();
        }
    }
    // acc -> az tile (all compute synced; az aliases stage buffers)
#pragma unroll
    for (int nf = 0; nf < 4; nf++)
#pragma unroll
        for (int r = 0; r < 4; r++)
            sm.az[wi * 16 + q * 4 + r][wd * 64 + nf * 16 + l15] = (half_t)acc[nf][r];
    __syncthreads();
#pragma unroll
    for (int it = 0; it < 2; it++) {
        int iloc = it * 32 + (t >> 4);         // 32 rows/pass, 16 lanes per row
        int i = i0 + iloc;
        int nb = b * 1024 + i;
        int R = c * 1024 + i;
        half8 az8 = *(const half8*)&sm.az[iloc][l15 * 8];
        half8 hv8 = *(const half8*)&hbr16[((size_t)nb << 7) + l15 * 8];
        float av[8], hv[8];
#pragma unroll
        for (int d = 0; d < 8; d++) {
            av[d] = fmaxf((float)az8[d], 0.f);
            hv[d] = (float)hv8[d];
        }
        float cf;
        if (mode >= 3) {
            const float* g1 = gw + l15 * 8;
            const float* g2 = gw + 128 + l15 * 8;
            float dp = 0.f;
#pragma unroll
            for (int d = 0; d < 8; d++) dp += hv[d] * g1[d] + av[d] * g2[d];
            dp += __shfl_xor(dp, 1); dp += __shfl_xor(dp, 2);
            dp += __shfl_xor(dp, 4); dp += __shfl_xor(dp, 8);
            cf = 1.f / (1.f + __expf(-(dp + gb_[0])));
            if (l15 == 0) cfb[R] = cf;
        } else {
            cf = cfb[R];
        }
        if (mode == 2 || mode == 4) {
            half8 o;
#pragma unroll
            for (int d = 0; d < 8; d++) o[d] = (half_t)(cf * hv[d] + (1.f - cf) * av[d]);
            *(half8*)&outR[(size_t)R * DD + l15 * 8] = o;
        } else {
            float sc = rsr[R];
#pragma unroll
            for (int d = 0; d < 8; d++)
                sm.az[iloc][l15 * 8 + d] = (half_t)(sc * (cf * hv[d] + (1.f - cf) * av[d]));
        }
    }
    if (mode == 1 || mode == 3) {
        __syncthreads();
        int d = t & 127, g4 = t >> 7;          // 4 i-chunks of 16
        half_t* op = outT + ((size_t)c * 128 + d) * 1024 + i0 + g4 * 16;
        half8 r0, r1;
#pragma unroll
        for (int e = 0; e < 8; e++) {
            r0[e] = sm.az[g4 * 16 + e][d];
            r1[e] = sm.az[g4 * 16 + 8 + e][d];
        }
        *(half8*)op = r0;
        *(half8*)(op + 8) = r1;
    }
}

// ---------------- partial masked pool of (z2 - z1), f16 inputs
__global__ __launch_bounds__(256)
void k_pool(const half_t* __restrict__ z2, const half_t* __restrict__ z1,
            const float* __restrict__ valid, float* __restrict__ part) {
    int b = blockIdx.y, s = blockIdx.x;
    int t = threadIdx.x, d = t & 127, hf = t >> 7;
    __shared__ float red[128];
    float acc = 0.f;
    int nbase = s * 128 + hf * 64;
    for (int n = nbase; n < nbase + 64; n++) {
        size_t gi = ((size_t)(b * 1024 + n) << 7) + d;
        acc += ((float)z2[gi] - (float)z1[gi]) * valid[b * 1024 + n];
    }
    if (hf) red[d] = acc;
    __syncthreads();
    if (!hf) part[(b * 8 + s) * 128 + d] = acc + red[d];
}

// ---------------- final reduce + MLP head
__global__ __launch_bounds__(128)
void k_mlp(const float* __restrict__ part, const float* __restrict__ valid,
           const float* __restrict__ w0, const float* __restrict__ b0,
           const float* __restrict__ w1, const float* __restrict__ b1,
           const float* __restrict__ w2, const float* __restrict__ b2,
           const float* __restrict__ w3, const float* __restrict__ b3,
           float* __restrict__ out) {
    int b = blockIdx.x, t = threadIdx.x;
    __shared__ float y0[DD], y1[DD];
    __shared__ float sred[2];
    float vs = 0.f;
    for (int n = t; n < NLEN; n += 128) vs += valid[b * NLEN + n];
    for (int off = 32; off; off >>= 1) vs += __shfl_down(vs, off);
    if ((t & 63) == 0) sred[t >> 6] = vs;
    __syncthreads();
    float vsum = sred[0] + sred[1];
    float acc = 0.f;
#pragma unroll
    for (int s = 0; s < 8; s++) acc += part[(b * 8 + s) * 128 + t];
    y0[t] = acc / vsum;
    __syncthreads();
    float a = b0[t];
    for (int k = 0; k < DD; k++) a += y0[k] * w0[t * DD + k];
    y1[t] = fmaxf(a, 0.f);
    __syncthreads();
    a = b1[t];
    for (int k = 0; k < DD; k++) a += y1[k] * w1[t * DD + k];
    y0[t] = fmaxf(a, 0.f);
    __syncthreads();
    a = b2[t];
    for (int k = 0; k < DD; k++) a += y0[k] * w2[t * DD + k];
    y1[t] = fmaxf(a, 0.f);
    __syncthreads();
    float pv = y1[t] * w3[t];
    for (int off = 32; off; off >>= 1) pv += __shfl_down(pv, off);
    if ((t & 63) == 0) sred[t >> 6] = pv;
    __syncthreads();
    if (t == 0) out[b] = 1.f / (1.f + __expf(-(sred[0] + sred[1] + b3[0])));
}

extern "C" void kernel_launch(void* const* d_in, const int* in_sizes, int n_in,
                              void* d_out, int out_size, void* d_ws, size_t ws_size,
                              hipStream_t stream) {
    (void)in_sizes; (void)n_in; (void)out_size; (void)ws_size;
    const float* x     = (const float*)d_in[0];
    const float* adj1  = (const float*)d_in[1];
    const float* adj2  = (const float*)d_in[2];
    const float* valid = (const float*)d_in[3];
    const float* Ew    = (const float*)d_in[4];
    const float* gW    = (const float*)d_in[5];
    const float* gb    = (const float*)d_in[6];
    const float* gA    = (const float*)d_in[7];
    const float* gatew = (const float*)d_in[8];
    const float* gateb = (const float*)d_in[9];
    const float* w0 = (const float*)d_in[10]; const float* b0 = (const float*)d_in[11];
    const float* w1 = (const float*)d_in[12]; const float* b1 = (const float*)d_in[13];
    const float* w2 = (const float*)d_in[14]; const float* b2 = (const float*)d_in[15];
    const float* w3 = (const float*)d_in[16]; const float* b3 = (const float*)d_in[17];
    float* out = (float*)d_out;

    char* p = (char*)d_ws;
    float* rsr  = (float*)p; p += 2 * BN * 4;
    float* cfb  = (float*)p; p += 2 * BN * 4;
    float* partb = (float*)p; p += (size_t)NB * 8 * 128 * 4;
    half_t* h16   = (half_t*)p; p += BND * 2;
    half_t* hbr16 = (half_t*)p; p += BND * 2;
    half_t* hbrF  = (half_t*)p; p += BND * 2;
    half_t* hSF   = (half_t*)p; p += BND * 2;
    half_t* hbrT  = (half_t*)p; p += BND * 2;       // [16 b][128 d][1024 i]
    half_t* hbrsT = (half_t*)p; p += 2 * BND * 2;   // [(br,b)][128 d][1024 i]
    half_t* zf    = (half_t*)p; p += 2 * BND * 2;   // layer outputs, row-major
    half_t* zTA   = (half_t*)p; p += 2 * BND * 2;   // hop buffers, transposed
    half_t* zTB   = (half_t*)p; p += 2 * BND * 2;
    unsigned short* mask16 = (unsigned short*)p; p += (size_t)2 * BN * 64 * 2;
    half_t* Dm   = (half_t*)p; p += (size_t)2 * BN * 1024 * 2;   // 64 MiB dense att
    half_t* Wf16 = (half_t*)p; p += (size_t)4 * 128 * 128 * 2;
    half_t* ST16 = (half_t*)p; p += (size_t)4 * 128 * 128 * 2;
    half_t* EwF  = (half_t*)p; p += (size_t)128 * 128 * 2;

    k_cast<<<320, 256, 0, stream>>>(gW, gA, Ew, Wf16, ST16, EwF);
    k_emb<<<512, 256, 0, stream>>>(x, EwF, h16);
    k_mask<<<8192, 256, 0, stream>>>(adj1, adj2, mask16);

    for (int k = 0; k < 4; k++) {
        int nhop = k + 1;
        const half_t* pa = k ? (zf + BND) : h16;
        const half_t* pb = k ? zf : nullptr;
        k_proj<<<512, 256, 0, stream>>>(pa, pb, Wf16 + (size_t)k * 16384, gb + k * 128,
                                        ST16 + (size_t)k * 16384, hbr16, hbrT, hbrF, hSF);
        k_E<<<dim3(64, NB), 256, 0, stream>>>(hSF, hbrF, mask16, hbrT, Dm, rsr, hbrsT);
        // hop 1 (gate computed in-kernel)
        if (nhop == 1) {
            k_azd<<<512, 512, 0, stream>>>(Dm, rsr, hbrsT, hbr16, gatew + k * 256, gateb + k,
                                           cfb, zf, (half_t*)nullptr, 4);
        } else {
            k_azd<<<512, 512, 0, stream>>>(Dm, rsr, hbrsT, hbr16, gatew + k * 256, gateb + k,
                                           cfb, (half_t*)nullptr, zTA, 3);
        }
        const half_t* srcT = zTA;
        for (int hop = 2; hop <= nhop; hop++) {
            if (hop == nhop) {
                k_azd<<<512, 512, 0, stream>>>(Dm, rsr, srcT, hbr16, gatew + k * 256, gateb + k,
                                               cfb, zf, (half_t*)nullptr, 2);
            } else {
                half_t* dT = (hop & 1) ? zTA : zTB;
                k_azd<<<512, 512, 0, stream>>>(Dm, rsr, srcT, hbr16, gatew + k * 256, gateb + k,
                                               cfb, (half_t*)nullptr, dT, 1);
                srcT = dT;
            }
        }
    }
    k_pool<<<dim3(8, NB), 256, 0, stream>>>(zf + BND, zf, valid, partb);
    k_mlp<<<16, 128, 0, stream>>>(partb, valid, w0, b0, w1, b1, w2, b2, w3, b3, out);
}